// Round 7
// baseline (490.063 us; speedup 1.0000x reference)
//
#include <hip/hip_runtime.h>
#include <hip/hip_bf16.h>

typedef __hip_bfloat16 bf16;
typedef __attribute__((ext_vector_type(8))) short short8;
typedef __attribute__((ext_vector_type(4))) float f32x4;
typedef __attribute__((ext_vector_type(8))) __bf16 bf16x8;
typedef const __attribute__((address_space(1))) void* gas_ptr;
typedef __attribute__((address_space(3))) void* las_ptr;

#define NB 32768
#define DD 768
#define AA 17
#define HH 128

__device__ __forceinline__ float bs2f(short s){
  unsigned int u = ((unsigned int)(unsigned short)s) << 16;
  return __builtin_bit_cast(float, u);
}
__device__ __forceinline__ short f2bs(float f){
  bf16 h = __float2bfloat16(f);
  return __builtin_bit_cast(short, h);
}
__device__ __forceinline__ f32x4 mfma16(short8 a, short8 b, f32x4 c){
  return __builtin_amdgcn_mfma_f32_16x16x32_bf16(
      __builtin_bit_cast(bf16x8, a), __builtin_bit_cast(bf16x8, b), c, 0, 0, 0);
}
// async global->LDS, 16B per lane; LDS dest is wave-uniform base + lane*16
__device__ __forceinline__ void glds16(const short* g, short* l){
  __builtin_amdgcn_global_load_lds((gas_ptr)g, (las_ptr)l, 16, 0, 0);
}

// load 8 consecutive elements starting at elem_off; convert to bf16 if F32
template<int F32>
__device__ __forceinline__ short8 ldchunk(const void* base, long elem_off){
  if (F32){
    const float4* p = (const float4*)((const float*)base + elem_off);
    float4 x = p[0], y = p[1];
    short8 r;
    r[0]=f2bs(x.x); r[1]=f2bs(x.y); r[2]=f2bs(x.z); r[3]=f2bs(x.w);
    r[4]=f2bs(y.x); r[5]=f2bs(y.y); r[6]=f2bs(y.z); r[7]=f2bs(y.w);
    return r;
  } else {
    return *(const short8*)((const short*)base + elem_off);
  }
}

// ---------------- prep kernels (all inputs fp32) ----------------

__device__ __forceinline__ float blk_mean128(float v, float* tmp){
  int t = threadIdx.x;
  #pragma unroll
  for (int m = 32; m; m >>= 1) v += __shfl_xor(v, m);
  if ((t & 63) == 0) tmp[t >> 6] = v;
  __syncthreads();
  float r = (tmp[0] + tmp[1]) * (1.0f / 128.0f);
  __syncthreads();
  return r;
}

__global__ void prep1(const float* __restrict__ w_tok, const float* __restrict__ b_tok,
                      const float* __restrict__ pos, const float* __restrict__ g_auln,
                      float* __restrict__ ug, float* __restrict__ rg, float* __restrict__ coef){
  __shared__ float tmp[2];
  int h = threadIdx.x;
  float w = w_tok[h];
  float wbar = blk_mean128(w, tmp);
  float u = w - wbar;
  float g = g_auln[h];
  ug[h] = u * g;
  float muu = blk_mean128(u * u, tmp);
  if (h == 0) coef[0] = muu;
  float bt = b_tok[h];
  for (int a = 0; a < AA; ++a){
    float c = bt + pos[a * HH + h];
    float cbar = blk_mean128(c, tmp);
    float r = c - cbar;
    rg[a * HH + h] = r * g;
    float mur = blk_mean128(u * r, tmp);
    float mrr = blk_mean128(r * r, tmp);
    if (h == 0){ coef[1 + a] = mur; coef[18 + a] = mrr; }
  }
}

__global__ void prep2(const float* __restrict__ w_in, const float* __restrict__ b_in,
                      const float* __restrict__ b_auln, const float* __restrict__ b_q,
                      const float* __restrict__ ug, const float* __restrict__ rg,
                      float* __restrict__ Uk, float* __restrict__ Ck,
                      float* __restrict__ Uv, float* __restrict__ Cv,
                      float* __restrict__ Rk, float* __restrict__ Rv,
                      float* __restrict__ bqf){
  int hp = threadIdx.x, bid = blockIdx.x;
  const float* wqrow = w_in + (long)hp * HH;
  const float* wkrow = w_in + (long)(HH + hp) * HH;
  const float* wvrow = w_in + (long)(2 * HH + hp) * HH;
  if (bid < AA){
    int a = bid;
    float sk = 0.f, sv = 0.f;
    for (int t = 0; t < HH; ++t){
      float r = rg[a * HH + t];
      sk += r * wkrow[t];
      sv += r * wvrow[t];
    }
    Rk[a * HH + hp] = sk; Rv[a * HH + hp] = sv;
  } else if (bid == AA){
    float uk = 0.f, uv = 0.f, ck = 0.f, cv = 0.f;
    for (int t = 0; t < HH; ++t){
      float u = ug[t], ba = b_auln[t];
      float wk = wkrow[t], wv = wvrow[t];
      uk += u * wk; uv += u * wv; ck += ba * wk; cv += ba * wv;
    }
    Uk[hp] = uk; Uv[hp] = uv;
    Ck[hp] = ck + b_in[HH + hp];
    Cv[hp] = cv + b_in[2 * HH + hp];
  } else {
    float s = 0.f;
    for (int t = 0; t < HH; ++t) s += b_q[t] * wqrow[t];
    bqf[hp] = s + b_in[hp];
  }
}

// Wqf[h][j] = sum_t w_in[h][t] * w_q[t][j]  (bf16 out, internal)
__global__ void prep_wqf(const float* __restrict__ w_in, const float* __restrict__ w_q,
                         bf16* __restrict__ Wqf){
  __shared__ float wq[HH];
  int h = blockIdx.x, t = threadIdx.x;
  if (t < HH) wq[t] = w_in[(long)h * HH + t];
  __syncthreads();
  for (int j = t; j < DD; j += 256){
    float acc = 0.f;
    for (int k = 0; k < HH; ++k) acc += wq[k] * w_q[(long)k * DD + j];
    Wqf[(long)h * DD + j] = __float2bfloat16(acc);
  }
}

// Gate-path precompute (one block per output column c of D):
//   Wg1b[c][j]  = bf16(w_gate[c][j])                      j<768   (phase-1 B)
//   Wg2w[c][t]  = bf16( sum_j w_gate[c][768+j]*w_out[j][t] )      (folded phase-2 B)
//   Woutb[c][t] = bf16(w_out[c][t])                               (af B)
//   bgp[c]      = b_gate[c] + sum_j w_gate[c][768+j]*b_out[j]
//   blocks c<HH additionally convert w_ao row c to bf16.
__global__ void prep_gate(const float* __restrict__ w_gate, const float* __restrict__ b_gate,
                          const float* __restrict__ w_out, const float* __restrict__ b_out,
                          const float* __restrict__ w_ao,
                          bf16* __restrict__ Wg1b, bf16* __restrict__ Wg2w,
                          bf16* __restrict__ Woutb, float* __restrict__ bgp,
                          bf16* __restrict__ w_ao_bf){
  __shared__ float wg2[DD];
  __shared__ float red[2];
  int c = blockIdx.x, t = threadIdx.x;
  const float* wrow = w_gate + (long)c * (2 * DD);
  for (int j = t; j < DD; j += 128){
    Wg1b[(long)c * DD + j] = __float2bfloat16(wrow[j]);
    wg2[j] = wrow[DD + j];
  }
  if (c < HH) w_ao_bf[(long)c * HH + t] = __float2bfloat16(w_ao[(long)c * HH + t]);
  __syncthreads();
  float acc = 0.f;
  for (int j = 0; j < DD; ++j) acc = fmaf(wg2[j], w_out[(long)j * HH + t], acc);
  Wg2w[(long)c * HH + t] = __float2bfloat16(acc);
  Woutb[(long)c * HH + t] = __float2bfloat16(w_out[(long)c * HH + t]);
  float pb = 0.f;
  for (int j = t; j < DD; j += 128) pb = fmaf(wg2[j], b_out[j], pb);
  #pragma unroll
  for (int m = 32; m; m >>= 1) pb += __shfl_xor(pb, m);
  if ((t & 63) == 0) red[t >> 6] = pb;
  __syncthreads();
  if (t == 0) bgp[c] = b_gate[c] + red[0] + red[1];
}

// ---------------- fused Q-GEMM + attention + aon-GEMM ----------------
// Per block (32 rows, 128 threads, 2 waves):
//   phase A: Q = visual @ Wqf^T + bqf          (K=768 MFMA, dbuf, SIDE-writes vbf)
//            Q tile -> LDS ep[32][136] (bf16)
//   phase B: attention in-place on ep (thread h owns column h; folded-K/V math,
//            32-lane shuffle reduce per head) -> ctx overwrites ep
//   phase C: aon = LN(ctx @ w_ao^T + b_ao)     (K=128 MFMA, w_ao glds-staged in halves)
// SIDE 1: write bf16 visual tile to sideA (pitch DD) during phase A.
template<int SIDE>
__global__ __launch_bounds__(128) void qaon(
    const float* __restrict__ visual, const bf16* __restrict__ Wqf,
    const float* __restrict__ bqf,
    const float* __restrict__ au, const float* __restrict__ coef,
    const float* __restrict__ Uk_, const float* __restrict__ Ck_,
    const float* __restrict__ Uv_, const float* __restrict__ Cv_,
    const float* __restrict__ Rk, const float* __restrict__ Rv,
    const bf16* __restrict__ w_ao_bf, const float* __restrict__ b_ao,
    const float* __restrict__ g_aln, const float* __restrict__ b_aln,
    short* __restrict__ sideA,
    bf16* __restrict__ aon)
{
  // shorts: [0,5120) bufA0 | [5120,10240) bufA1 | [10240,11328) au(f32) |
  // [11328,15680) ep 32x136 | phase C: w_ao chunks [0,4096),[4096,8192); LN ep2 [0,4352)
  __shared__ __align__(16) short smem[16384];
  const int tid = threadIdx.x;
  const int wv = tid >> 6, l = tid & 63;
  const long rowBase = (long)blockIdx.x * 32;
  const int fr = l & 15, kq = l >> 4;
  const int swofs = (kq ^ ((l >> 1) & 3)) << 3;       // swizzled read slot
  const int arow = tid >> 2, ac = tid & 3;            // A staging row/chunk
  const int asl = (ac ^ ((arow >> 1) & 3)) * 8;       // swizzled A write slot
  const int srow = l >> 2;                            // glds row within 16-group
  const int schunk = ((l & 3) ^ ((l >> 3) & 3)) * 8;  // glds source chunk (pre-swizzle)

  // stage au rows [rowBase, rowBase+32): 544 floats
  float* auS = (float*)(smem + 10240);
  for (int idx = tid; idx < 32 * AA; idx += 128) auS[idx] = au[rowBase * AA + idx];

  // ---- phase A: Q = visual @ Wqf^T + bqf (K = 768) ----
  f32x4 acc[8];
  f32x4 zero = {0.f, 0.f, 0.f, 0.f};
  #pragma unroll
  for (int j = 0; j < 8; ++j) acc[j] = zero;

  short8 avh;
  {
    short8 av0 = ldchunk<1>(visual, (rowBase + arow) * (long)DD + ac * 8);
    if (SIDE) *(short8*)(sideA + (rowBase + arow) * DD + ac * 8) = av0;
    *(short8*)(smem + arow * 32 + asl) = av0;
    #pragma unroll
    for (int i = 0; i < 4; ++i){
      const int brow = wv * 64 + i * 16 + srow;
      glds16((const short*)Wqf + (long)brow * DD + schunk,
             smem + 1024 + wv * 2048 + i * 512);
    }
    avh = ldchunk<1>(visual, (rowBase + arow) * (long)DD + 32 + ac * 8);
    if (SIDE) *(short8*)(sideA + (rowBase + arow) * DD + 32 + ac * 8) = avh;
  }
  for (int kt = 0; kt < DD / 32; ++kt){
    __syncthreads();   // buf[kt] staged (glds drained, ds_writes visible)
    short* cb = smem + (kt & 1) * 5120;
    short* nb = smem + ((kt + 1) & 1) * 5120;
    if (kt + 1 < DD / 32){
      *(short8*)(nb + arow * 32 + asl) = avh;
      const long kB = (long)(kt + 1) * 32;
      #pragma unroll
      for (int i = 0; i < 4; ++i){
        const int brow = wv * 64 + i * 16 + srow;
        glds16((const short*)Wqf + (long)brow * DD + kB + schunk,
               nb + 1024 + wv * 2048 + i * 512);
      }
      if (kt + 2 < DD / 32){
        const long kA = (long)(kt + 2) * 32;
        avh = ldchunk<1>(visual, (rowBase + arow) * (long)DD + kA + ac * 8);
        if (SIDE) *(short8*)(sideA + (rowBase + arow) * DD + kA + ac * 8) = avh;
      }
    }
    const int ra = wv * 16 + fr;
    short8 a0 = *(const short8*)(cb + ra * 32 + swofs);
    #pragma unroll
    for (int nt = 0; nt < 8; ++nt){
      short8 b = *(const short8*)(cb + 1024 + (nt * 16 + fr) * 32 + swofs);
      acc[nt] = mfma16(a0, b, acc[nt]);
    }
  }
  __syncthreads();

  // Q epilogue -> ep (linear [32][136] bf16)
  short* ep = smem + 11328;
  #pragma unroll
  for (int nt = 0; nt < 8; ++nt){
    const float bv = bqf[nt * 16 + fr];
    #pragma unroll
    for (int r = 0; r < 4; ++r)
      ep[(wv * 16 + kq * 4 + r) * 136 + nt * 16 + fr] = f2bs(acc[nt][r] + bv);
  }
  __syncthreads();

  // ---- phase B: attention (folded K/V), ctx overwrites ep ----
  {
    const int h = tid;
    const float Uk = Uk_[h], Ck = Ck_[h], Uv = Uv_[h], Cv = Cv_[h];
    const float cA = coef[0];
    float rk[AA], rv[AA];
    #pragma unroll
    for (int a = 0; a < AA; ++a){ rk[a] = Rk[a * HH + h]; rv[a] = Rv[a * HH + h]; }
    const float scale = 0.17677669529663689f; // 1/sqrt(32)
    for (int r = 0; r < 32; ++r){
      float q = bs2f(ep[r * 136 + h]);
      float sc[AA], vvv[AA];
      #pragma unroll
      for (int a = 0; a < AA; ++a){
        float s = auS[r * AA + a];
        float var = fmaf(s * s, cA, fmaf(2.f * s, coef[1 + a], coef[18 + a]));
        float rinv = rsqrtf(fmaxf(var, 0.f) + 1e-5f);
        float kk = fmaf(s, Uk, rk[a]) * rinv + Ck;
        vvv[a]   = fmaf(s, Uv, rv[a]) * rinv + Cv;
        float p = q * kk;
        p += __shfl_xor(p, 16); p += __shfl_xor(p, 8); p += __shfl_xor(p, 4);
        p += __shfl_xor(p, 2);  p += __shfl_xor(p, 1);
        sc[a] = p * scale;
      }
      float mx = sc[0];
      #pragma unroll
      for (int a = 1; a < AA; ++a) mx = fmaxf(mx, sc[a]);
      float den = 0.f, cval = 0.f;
      #pragma unroll
      for (int a = 0; a < AA; ++a){
        float e = __expf(sc[a] - mx);
        den += e; cval += e * vvv[a];
      }
      ep[r * 136 + h] = f2bs(cval / den);   // each (r,h) touched only by thread h
    }
  }
  __syncthreads();

  // ---- phase C: aon = LN(ctx @ w_ao^T + b_ao), K = 128 ----
  f32x4 acc2[8];
  #pragma unroll
  for (int j = 0; j < 8; ++j) acc2[j] = zero;
  for (int kh = 0; kh < 2; ++kh){
    __syncthreads();   // prior reads of smem[0,8192) done
    #pragma unroll
    for (int c = 0; c < 2; ++c){
      const int kc = (kh * 2 + c) * 32;
      #pragma unroll
      for (int i = 0; i < 4; ++i){
        const int row = wv * 64 + i * 16 + srow;
        glds16((const short*)w_ao_bf + (long)row * HH + kc + schunk,
               smem + c * 4096 + wv * 2048 + i * 512);
      }
    }
    __syncthreads();   // glds drained
    #pragma unroll
    for (int c = 0; c < 2; ++c){
      const int kt = kh * 2 + c;
      short8 a0 = *(const short8*)(ep + (wv * 16 + fr) * 136 + kt * 32 + kq * 8);
      #pragma unroll
      for (int nt = 0; nt < 8; ++nt){
        short8 b = *(const short8*)(smem + c * 4096 + (nt * 16 + fr) * 32 + swofs);
        acc2[nt] = mfma16(a0, b, acc2[nt]);
      }
    }
  }
  __syncthreads();   // MFMA reads done; smem[0,*) reusable

  // LN epilogue -> ep2, then coalesced store to aon
  short* ep2 = smem;
  #pragma unroll
  for (int r = 0; r < 4; ++r){
    float x[8]; float sm = 0.f, sq = 0.f;
    #pragma unroll
    for (int nt = 0; nt < 8; ++nt){
      x[nt] = acc2[nt][r] + b_ao[nt * 16 + fr];
      sm += x[nt]; sq += x[nt] * x[nt];
    }
    sm += __shfl_xor(sm, 1); sq += __shfl_xor(sq, 1);
    sm += __shfl_xor(sm, 2); sq += __shfl_xor(sq, 2);
    sm += __shfl_xor(sm, 4); sq += __shfl_xor(sq, 4);
    sm += __shfl_xor(sm, 8); sq += __shfl_xor(sq, 8);
    const float mu = sm * (1.f / 128.f);
    const float var = sq * (1.f / 128.f) - mu * mu;
    const float rinv = rsqrtf(fmaxf(var, 0.f) + 1e-5f);
    const int lrow = wv * 16 + kq * 4 + r;
    #pragma unroll
    for (int nt = 0; nt < 8; ++nt){
      const int col = nt * 16 + fr;
      float y = (x[nt] - mu) * rinv * g_aln[col] + b_aln[col];
      ep2[lrow * 136 + col] = f2bs(y);
    }
  }
  __syncthreads();
  #pragma unroll
  for (int it = 0; it < 4; ++it){
    const int cid = tid + it * 128;
    const int rw = cid >> 4;
    const int cc = (cid & 15) * 8;
    *(short8*)((short*)aon + (rowBase + rw) * HH + cc) = *(const short8*)(ep2 + rw * 136 + cc);
  }
}

// ---------------- fused gate GEMM (128 x 64 tiles) ----------------
// accG = A1(visual) @ Wg1b^T  (K=768)  +  aon @ Wg2w^T (K=128)  [gate logits]
// accF = aon @ Woutb^T        (K=128)                           [attn_feat tile]
// out  = sigmoid(accG+bgp) * (accF+b_out) + (1-gate) * visual_fp32
// Phase 1 (A1F=0): glds 3-buffer 2-deep pipeline, raw s_barrier + counted vmcnt
//   (vmcnt(3) per K-step, never 0 mid-loop); stage issued AFTER the barrier so the
//   overwritten buffer's readers are provably done. (A1F=1): reg-staged fallback.
// Phase 2: glds single-buffer, 2 barriers/K-step (all operands internal bf16).
template<int A1F>
__global__ __launch_bounds__(256) void gemm_final(
    const void* __restrict__ A1,           // visual: bf16 (A1F=0) or fp32 (A1F=1), pitch DD
    const bf16* __restrict__ aon,          // NB x HH
    const bf16* __restrict__ Wg1b,         // DD x DD
    const bf16* __restrict__ Wg2w,         // DD x HH
    const bf16* __restrict__ Woutb,        // DD x HH
    const float* __restrict__ bgp,         // DD (folded gate bias)
    const float* __restrict__ b_out,       // DD
    const float* __restrict__ vf,          // visual fp32 (epilogue mix)
    float* __restrict__ C)                 // NB x DD fp32
{
  // phase1 buf p (p=0..2) at p*6144 shorts: A [0,4096) 128x32, B [4096,6144) 64x32.
  // phase2 (single buf): A [0,4096), B1 [4096,6144), B2 [6144,8192).
  __shared__ __align__(16) short smem[18432];  // 36 KB
  const int tid = threadIdx.x;
  const int wv = tid >> 6, l = tid & 63;

  // bijective XCD swizzle: nwg = 12*256 = 3072, divisible by 8.
  const int nx = 12;
  const int bid = blockIdx.y * nx + blockIdx.x;
  const int cpx = (NB / 128) * nx / 8;            // 384 blocks per XCD chunk
  const int swz = (bid & 7) * cpx + (bid >> 3);
  const long rowBase = (long)(swz / nx) * 128;
  const int colBase = (swz % nx) * 64;

  const int fr = l & 15;
  const int kq = l >> 4;
  const int swofs = (kq ^ ((l >> 1) & 3)) << 3;
  const int srow = l >> 2;
  const int schunk = ((l & 3) ^ ((l >> 3) & 3)) * 8;

  f32x4 accG[2][4], accF[2][4];
  f32x4 zero = {0.f, 0.f, 0.f, 0.f};
  #pragma unroll
  for (int i = 0; i < 2; ++i)
    #pragma unroll
    for (int j = 0; j < 4; ++j){ accG[i][j] = zero; accF[i][j] = zero; }

  // ---- phase 1: visual @ Wg1b^T (cols colBase..+64), K = 768 ----
  if (A1F == 0){
    const short* Ab = (const short*)A1;
    const short* Bb = (const short*)Wg1b;
    // 3 glds per wave per stage (2 A + 1 B)
    #define STAGE_F1(p, kt) {                                                 \
      short* d = smem + (p) * 6144;                                           \
      _Pragma("unroll")                                                       \
      for (int i = 0; i < 2; ++i){                                            \
        const int r = wv * 32 + i * 16 + srow;                                \
        glds16(Ab + (rowBase + r) * (long)DD + (kt) * 32 + schunk,            \
               d + wv * 1024 + i * 512);                                      \
      }                                                                       \
      glds16(Bb + (long)(colBase + wv * 16 + srow) * DD + (kt) * 32 + schunk, \
             d + 4096 + wv * 512);                                            \
    }
    STAGE_F1(0, 0);
    STAGE_F1(1, 1);
    for (int kt = 0; kt < DD / 32; ++kt){
      // glds(kt) landed when all but the newest 3 (= glds(kt+1)) have retired
      if (kt < DD / 32 - 1) asm volatile("s_waitcnt vmcnt(3)" ::: "memory");
      else                  asm volatile("s_waitcnt vmcnt(0)" ::: "memory");
      __builtin_amdgcn_s_barrier();   // all waves: buf kt landed; prior reads done
      if (kt + 2 < DD / 32) STAGE_F1((kt + 2) % 3, kt + 2);
      short* cb = smem + (kt % 3) * 6144;
      const int ra0 = wv * 32 + fr;
      short8 a0 = *(const short8*)(cb + ra0 * 32 + swofs);
      short8 a1 = *(const short8*)(cb + (ra0 + 16) * 32 + swofs);
      #pragma unroll
      for (int nt = 0; nt < 4; ++nt){
        short8 b = *(const short8*)(cb + 4096 + (nt * 16 + fr) * 32 + swofs);
        accG[0][nt] = mfma16(a0, b, accG[0][nt]);
        accG[1][nt] = mfma16(a1, b, accG[1][nt]);
      }
    }
    #undef STAGE_F1
  } else {
    // fallback: fp32 A reg-staged, single buffer [0,6144), 2 barriers per K-step
    const int r0 = tid >> 2, ac = tid & 3;
    const int s0 = (ac ^ ((r0 >> 1) & 3)) * 8;   // same for r0 and r0+64
    for (int kt = 0; kt < DD / 32; ++kt){
      const long kA = (long)kt * 32;
      short8 av0 = ldchunk<1>(A1, (rowBase + r0) * (long)DD + kA + ac * 8);
      short8 av1 = ldchunk<1>(A1, (rowBase + 64 + r0) * (long)DD + kA + ac * 8);
      short8 bv  = *(const short8*)((const short*)Wg1b + (long)(colBase + r0) * DD + kA + ac * 8);
      __syncthreads();
      *(short8*)(smem + r0 * 32 + s0) = av0;
      *(short8*)(smem + (64 + r0) * 32 + s0) = av1;
      *(short8*)(smem + 4096 + r0 * 32 + s0) = bv;
      __syncthreads();
      const int ra0 = wv * 32 + fr;
      short8 a0 = *(const short8*)(smem + ra0 * 32 + swofs);
      short8 a1 = *(const short8*)(smem + (ra0 + 16) * 32 + swofs);
      #pragma unroll
      for (int nt = 0; nt < 4; ++nt){
        short8 b = *(const short8*)(smem + 4096 + (nt * 16 + fr) * 32 + swofs);
        accG[0][nt] = mfma16(a0, b, accG[0][nt]);
        accG[1][nt] = mfma16(a1, b, accG[1][nt]);
      }
    }
  }

  // ---- phase 2: aon @ {Wg2w, Woutb}^T, K = 128, glds single-buffer ----
  for (int kt = 0; kt < HH / 32; ++kt){
    __syncthreads();             // prior reads (phase1 tail / prior kt) done; drains all
    const long kA = (long)kt * 32;
    #pragma unroll
    for (int i = 0; i < 2; ++i){
      const int r = wv * 32 + i * 16 + srow;
      glds16((const short*)aon + (rowBase + r) * HH + kA + schunk,
             smem + wv * 1024 + i * 512);
    }
    glds16((const short*)Wg2w + (long)(colBase + wv * 16 + srow) * HH + kA + schunk,
           smem + 4096 + wv * 512);
    glds16((const short*)Woutb + (long)(colBase + wv * 16 + srow) * HH + kA + schunk,
           smem + 6144 + wv * 512);
    __syncthreads();             // glds drained
    const int ra0 = wv * 32 + fr;
    short8 a0 = *(const short8*)(smem + ra0 * 32 + swofs);
    short8 a1 = *(const short8*)(smem + (ra0 + 16) * 32 + swofs);
    #pragma unroll
    for (int nt = 0; nt < 4; ++nt){
      short8 b  = *(const short8*)(smem + 4096 + (nt * 16 + fr) * 32 + swofs);
      short8 b2 = *(const short8*)(smem + 6144 + (nt * 16 + fr) * 32 + swofs);
      accG[0][nt] = mfma16(a0, b,  accG[0][nt]);
      accG[1][nt] = mfma16(a1, b,  accG[1][nt]);
      accF[0][nt] = mfma16(a0, b2, accF[0][nt]);
      accF[1][nt] = mfma16(a1, b2, accF[1][nt]);
    }
  }

  // ---- epilogue: gate-mix directly from registers (fp32 out) ----
  float bg[4], bo[4];
  #pragma unroll
  for (int nt = 0; nt < 4; ++nt){
    const int col = colBase + nt * 16 + fr;
    bg[nt] = bgp[col];
    bo[nt] = b_out[col];
  }
  #pragma unroll
  for (int mt = 0; mt < 2; ++mt){
    const long r0 = rowBase + wv * 32 + mt * 16 + kq * 4;
    #pragma unroll
    for (int r = 0; r < 4; ++r){
      const long row = r0 + r;
      const float* vrow = vf + row * DD;
      float* crow = C + row * DD;
      #pragma unroll
      for (int nt = 0; nt < 4; ++nt){
        const int col = colBase + nt * 16 + fr;
        const float lin = accG[mt][nt][r] + bg[nt];
        const float afv = accF[mt][nt][r] + bo[nt];
        const float gate = 1.f / (1.f + __expf(-lin));
        crow[col] = gate * afv + (1.f - gate) * vrow[col];
      }
    }
  }
}

// ---------------- launch ----------------
// d_out carve (dead before gemm_final writes d_out): tables at [16,~16.5) MB.
// d_ws: aon + gate tables (~9.6 MB) + optional vbf 48 MB (engaged only if ws_size
// is large enough; all gemm_final INPUTS live outside d_out).
extern "C" void kernel_launch(void* const* d_in, const int* in_sizes, int n_in,
                              void* d_out, int out_size, void* d_ws, size_t ws_size,
                              hipStream_t stream){
  const float* visual = (const float*)d_in[0];
  const float* au     = (const float*)d_in[1];
  const float* w_tok  = (const float*)d_in[2];
  const float* b_tok  = (const float*)d_in[3];
  const float* pos    = (const float*)d_in[4];
  const float* g_auln = (const float*)d_in[5];
  const float* b_auln = (const float*)d_in[6];
  const float* w_q    = (const float*)d_in[7];
  const float* b_q    = (const float*)d_in[8];
  const float* w_in   = (const float*)d_in[9];
  const float* b_in   = (const float*)d_in[10];
  const float* w_ao   = (const float*)d_in[11];
  const float* b_ao   = (const float*)d_in[12];
  const float* g_aln  = (const float*)d_in[13];
  const float* b_aln  = (const float*)d_in[14];
  const float* w_out  = (const float*)d_in[15];
  const float* b_out  = (const float*)d_in[16];
  const float* w_gate = (const float*)d_in[17];
  const float* b_gate = (const float*)d_in[18];

  char* ob = (char*)d_out;
  char* p = ob + ((size_t)16 << 20);             // tables (read only by pre-final kernels)
  auto alloc = [&](size_t bytes){ char* r = p; p += (bytes + 255) & ~(size_t)255; return r; };
  bf16*  Wqf     = (bf16*) alloc((size_t)HH * DD * 2);
  bf16*  w_ao_bf = (bf16*) alloc((size_t)HH * HH * 2);
  float* bqf  = (float*)alloc(HH * 4);
  float* ug   = (float*)alloc(HH * 4);
  float* rg   = (float*)alloc(AA * HH * 4);
  float* coef = (float*)alloc(64 * 4);
  float* Uk   = (float*)alloc(HH * 4);
  float* Ck   = (float*)alloc(HH * 4);
  float* Uv   = (float*)alloc(HH * 4);
  float* Cv   = (float*)alloc(HH * 4);
  float* Rk   = (float*)alloc(AA * HH * 4);
  float* Rv   = (float*)alloc(AA * HH * 4);

  // workspace carve: everything gemm_final READS must live here (it rewrites d_out)
  char* q = (char*)d_ws;
  auto walloc = [&](size_t bytes){ char* r = q; q += (bytes + 255) & ~(size_t)255; return r; };
  bf16*  aon   = (bf16*) walloc((size_t)NB * HH * 2);   // 8 MB
  bf16*  Wg1b  = (bf16*) walloc((size_t)DD * DD * 2);   // 1.125 MB
  bf16*  Wg2w  = (bf16*) walloc((size_t)DD * HH * 2);   // 192 KB
  bf16*  Woutb = (bf16*) walloc((size_t)DD * HH * 2);   // 192 KB
  float* bgp   = (float*)walloc(DD * 4);
  bf16*  vbf   = (bf16*) walloc((size_t)NB * DD * 2);   // 48 MB (optional)
  const bool use_vbf = (size_t)(q - (char*)d_ws) <= ws_size;

  prep1<<<dim3(1), dim3(128), 0, stream>>>(w_tok, b_tok, pos, g_auln, ug, rg, coef);
  prep2<<<dim3(19), dim3(128), 0, stream>>>(w_in, b_in, b_auln, b_q, ug, rg, Uk, Ck, Uv, Cv, Rk, Rv, bqf);
  prep_wqf<<<dim3(128), dim3(256), 0, stream>>>(w_in, w_q, Wqf);
  prep_gate<<<dim3(DD), dim3(128), 0, stream>>>(w_gate, b_gate, w_out, b_out, w_ao,
                                                Wg1b, Wg2w, Woutb, bgp, w_ao_bf);

  // fused: Q-GEMM + attention + aon-GEMM (side-writes visual_bf16 if workspace fits)
  if (use_vbf)
    qaon<1><<<dim3(NB / 32), dim3(128), 0, stream>>>(
        visual, Wqf, bqf, au, coef, Uk, Ck, Uv, Cv, Rk, Rv,
        w_ao_bf, b_ao, g_aln, b_aln, (short*)vbf, aon);
  else
    qaon<0><<<dim3(NB / 32), dim3(128), 0, stream>>>(
        visual, Wqf, bqf, au, coef, Uk, Ck, Uv, Cv, Rk, Rv,
        w_ao_bf, b_ao, g_aln, b_aln, nullptr, aon);

  // out = sigmoid(visual@Wg1^T + aon@Wg2w^T + bgp) * (aon@Woutb^T + b_out) + (1-g)*visual
  if (use_vbf)
    gemm_final<0><<<dim3(12, NB / 128), dim3(256), 0, stream>>>(
        vbf, aon, Wg1b, Wg2w, Woutb, bgp, b_out, visual, (float*)d_out);
  else
    gemm_final<1><<<dim3(12, NB / 128), dim3(256), 0, stream>>>(
        visual, aon, Wg1b, Wg2w, Woutb, bgp, b_out, visual, (float*)d_out);
}